// Round 1
// baseline (2310.953 us; speedup 1.0000x reference)
//
#include <hip/hip_runtime.h>

// Problem constants (B=64, T=512, D=256, Q=8, K=1024)
#define NTOK   32768   // B*T
#define DDIM   256
#define KCODES 1024
#define QLAYERS 8

// Tiling
#define MT 64   // tokens per block
#define KT 64   // codes per K-chunk
#define DC 32   // D-chunk staged in LDS
#define LDP 68  // padded LDS row stride (multiple of 4 -> 16B-aligned float4 rows)

// d_out layout: [0, N*D) residual->output | [N*D] loss | [N*D+1, +Q*N) indices (as float)

__global__ void ce_kernel(const float* __restrict__ emb, float* __restrict__ ce) {
  int gid  = blockIdx.x * blockDim.x + threadIdx.x;
  int code = gid >> 6;                 // one wave per code, Q*K codes total
  int lane = threadIdx.x & 63;
  float4 v = reinterpret_cast<const float4*>(emb + (size_t)code * DDIM)[lane];
  float s = v.x * v.x + v.y * v.y + v.z * v.z + v.w * v.w;
#pragma unroll
  for (int off = 32; off; off >>= 1) s += __shfl_xor(s, off);
  if (lane == 0) ce[code] = s;
}

__global__ void init_kernel(const float* __restrict__ x, float* __restrict__ out) {
  size_t i = (size_t)blockIdx.x * blockDim.x + threadIdx.x;
  reinterpret_cast<float4*>(out)[i] = reinterpret_cast<const float4*>(x)[i];
  if (i == 0) out[(size_t)NTOK * DDIM] = 0.0f;   // zero loss accumulator
}

__global__ __launch_bounds__(256)
void vq_layer_kernel(const float* __restrict__ emb,      // this layer's codebook [K][D]
                     const float* __restrict__ ce,       // [K] = ||e_k||^2
                     float* __restrict__ res,            // residual [N][D] (lives in d_out)
                     float* __restrict__ idx_out,        // [N] floats (this layer's slice)
                     float* __restrict__ loss_accum) {
  __shared__ __align__(16) float As[DC][LDP];
  __shared__ __align__(16) float Bs[DC][LDP];
  __shared__ float cf_s[MT];
  __shared__ float ce_s[KT];
  __shared__ float redv[MT][17];
  __shared__ int   redi[MT][17];
  __shared__ int   idx_s[MT];
  __shared__ float wsum[4];

  const int t    = threadIdx.x;
  const int tx   = t & 15;
  const int ty   = t >> 4;
  const int tok0 = blockIdx.x * MT;

  // ---- phase 1: cf = ||residual||^2 per token (4 threads per token) ----
  {
    const int m = t >> 2, p = t & 3;
    const float4* r4 =
        reinterpret_cast<const float4*>(res + (size_t)(tok0 + m) * DDIM + p * 64);
    float s = 0.f;
#pragma unroll
    for (int j = 0; j < 16; ++j) {
      float4 v = r4[j];
      s = fmaf(v.x, v.x, s); s = fmaf(v.y, v.y, s);
      s = fmaf(v.z, v.z, s); s = fmaf(v.w, v.w, s);
    }
    s += __shfl_xor(s, 1);
    s += __shfl_xor(s, 2);
    if (p == 0) cf_s[m] = s;
  }

  float minv[4]; int mini[4];
#pragma unroll
  for (int i = 0; i < 4; ++i) { minv[i] = 3.4e38f; mini[i] = 0; }

  // ---- phase 2: distances + running argmin, K in chunks of KT ----
  for (int kc = 0; kc < KCODES / KT; ++kc) {
    __syncthreads();                       // guards ce_s rewrite vs prev epilogue
    if (t < KT) ce_s[t] = ce[kc * KT + t];

    float acc[4][4];
#pragma unroll
    for (int i = 0; i < 4; ++i)
#pragma unroll
      for (int j = 0; j < 4; ++j) acc[i][j] = 0.f;

    for (int dc = 0; dc < DDIM / DC; ++dc) {
      __syncthreads();                     // guards As/Bs rewrite vs prev compute
      {
        int u = t * 2;
#pragma unroll
        for (int i = 0; i < 2; ++i, ++u) { // stage A (tokens), transposed
          int m = u >> 3, dq = (u & 7) * 4;
          float4 v = *reinterpret_cast<const float4*>(
              res + (size_t)(tok0 + m) * DDIM + dc * DC + dq);
          As[dq + 0][m] = v.x; As[dq + 1][m] = v.y;
          As[dq + 2][m] = v.z; As[dq + 3][m] = v.w;
        }
        u = t * 2;
#pragma unroll
        for (int i = 0; i < 2; ++i, ++u) { // stage B (codes), transposed
          int c = u >> 3, dq = (u & 7) * 4;
          float4 v = *reinterpret_cast<const float4*>(
              emb + (size_t)(kc * KT + c) * DDIM + dc * DC + dq);
          Bs[dq + 0][c] = v.x; Bs[dq + 1][c] = v.y;
          Bs[dq + 2][c] = v.z; Bs[dq + 3][c] = v.w;
        }
      }
      __syncthreads();
#pragma unroll
      for (int d = 0; d < DC; ++d) {
        const float4 a = *reinterpret_cast<const float4*>(&As[d][ty * 4]);
        const float4 b = *reinterpret_cast<const float4*>(&Bs[d][tx * 4]);
        const float av[4] = {a.x, a.y, a.z, a.w};
        const float bv[4] = {b.x, b.y, b.z, b.w};
#pragma unroll
        for (int i = 0; i < 4; ++i)
#pragma unroll
          for (int j = 0; j < 4; ++j) acc[i][j] = fmaf(av[i], bv[j], acc[i][j]);
      }
    }

    // epilogue: replicate reference rounding  dist = fl(fl(cf+ce) - 2*dot)
#pragma unroll
    for (int i = 0; i < 4; ++i) {
      const float cf = cf_s[ty * 4 + i];
#pragma unroll
      for (int j = 0; j < 4; ++j) {
        float t1   = cf + ce_s[tx * 4 + j];
        float dist = t1 - 2.0f * acc[i][j];
        int   c    = kc * KT + tx * 4 + j;
        if (dist < minv[i]) { minv[i] = dist; mini[i] = c; }  // strict < : first index wins
      }
    }
  }

  // ---- phase 3: cross-thread argmin reduce (tie-break: lowest code index) ----
#pragma unroll
  for (int i = 0; i < 4; ++i) {
    redv[ty * 4 + i][tx] = minv[i];
    redi[ty * 4 + i][tx] = mini[i];
  }
  __syncthreads();
  if (t < MT) {
    float bv_ = redv[t][0]; int bi_ = redi[t][0];
#pragma unroll
    for (int j = 1; j < 16; ++j) {
      float v = redv[t][j]; int c = redi[t][j];
      if (v < bv_ || (v == bv_ && c < bi_)) { bv_ = v; bi_ = c; }
    }
    idx_s[t] = bi_;
    idx_out[tok0 + t] = (float)bi_;
  }
  __syncthreads();

  // ---- phase 4: residual -= emb[idx]; loss += 1.25*mean(new_res^2) ----
  {
    const int m = t >> 2, p = t & 3;
    const int ci = idx_s[m];
    const float4* e4 =
        reinterpret_cast<const float4*>(emb + (size_t)ci * DDIM + p * 64);
    float4* r4 = reinterpret_cast<float4*>(res + (size_t)(tok0 + m) * DDIM + p * 64);
    float s = 0.f;
#pragma unroll
    for (int j = 0; j < 16; ++j) {
      float4 r = r4[j], e = e4[j];
      float4 nr = make_float4(r.x - e.x, r.y - e.y, r.z - e.z, r.w - e.w);
      s = fmaf(nr.x, nr.x, s); s = fmaf(nr.y, nr.y, s);
      s = fmaf(nr.z, nr.z, s); s = fmaf(nr.w, nr.w, s);
      r4[j] = nr;
    }
#pragma unroll
    for (int off = 32; off; off >>= 1) s += __shfl_xor(s, off);
    if ((t & 63) == 0) wsum[t >> 6] = s;
  }
  __syncthreads();
  if (t == 0) {
    float total = wsum[0] + wsum[1] + wsum[2] + wsum[3];
    atomicAdd(loss_accum, total * (1.25f / ((float)NTOK * (float)DDIM)));
  }
}

__global__ void final_kernel(const float* __restrict__ x, float* __restrict__ out) {
  size_t i = (size_t)blockIdx.x * blockDim.x + threadIdx.x;
  float4 xv = reinterpret_cast<const float4*>(x)[i];
  float4 r  = reinterpret_cast<float4*>(out)[i];
  reinterpret_cast<float4*>(out)[i] =
      make_float4(xv.x - r.x, xv.y - r.y, xv.z - r.z, xv.w - r.w);
}

extern "C" void kernel_launch(void* const* d_in, const int* in_sizes, int n_in,
                              void* d_out, int out_size, void* d_ws, size_t ws_size,
                              hipStream_t stream) {
  const float* x   = (const float*)d_in[0];
  const float* emb = (const float*)d_in[1];
  float* out      = (float*)d_out;
  float* ce       = (float*)d_ws;                       // Q*K floats = 32 KB
  float* loss     = out + (size_t)NTOK * DDIM;
  float* idx_base = loss + 1;

  ce_kernel<<<QLAYERS * KCODES * 64 / 256, 256, 0, stream>>>(emb, ce);
  init_kernel<<<NTOK * DDIM / 4 / 256, 256, 0, stream>>>(x, out);
  for (int q = 0; q < QLAYERS; ++q) {
    vq_layer_kernel<<<NTOK / MT, 256, 0, stream>>>(
        emb + (size_t)q * KCODES * DDIM, ce + (size_t)q * KCODES, out,
        idx_base + (size_t)q * NTOK, loss);
  }
  final_kernel<<<NTOK * DDIM / 4 / 256, 256, 0, stream>>>(x, out);
}